// Round 11
// baseline (473.459 us; speedup 1.0000x reference)
//
#include <hip/hip_runtime.h>
#include <hip/hip_bf16.h>

typedef __attribute__((ext_vector_type(8))) short s8v;
typedef __attribute__((ext_vector_type(4))) float f4v;
typedef __hip_bfloat16 bf16;

// ---- problem constants ----
#define BSZ 4
#define SEQ 1024
#define IDIM 4096
#define RNK 512
#define RPD 64
#define NH 32
#define HD 128
#define BT 4096   // BSZ*SEQ tokens

__device__ __forceinline__ void load_lds16(const bf16* g, bf16* l) {
  __builtin_amdgcn_global_load_lds((const __attribute__((address_space(1))) void*)g,
                                   (__attribute__((address_space(3))) void*)l, 16, 0, 0);
}

// =====================================================================
// 256x256 8-wave bf16 GEMM v5 — BK=32, SOFTWARE-PIPELINED register reads.
// Per tile: 4 phases; phase p issues {ds_reads for phase p+1 (2-6), 1 gload,
// 8 MFMA on regs read in phase p-1, barrier}. Operand reads are a full phase
// ahead of consumption, so their LDS latency hides under the MFMA window and
// the compiler emits COUNTED lgkm waits (newer read-aheads stay pending).
// Stage map (tile u buf u&1): A(u+1)->As[~u&1] @P0-P1; B(u+2)->Bs[u&1] @P2-P3
// (Bs[u&1]'s only read is at tile u-1 P3 read-ahead — sealed by barriers).
// Gate: single vmcnt(1) per tile at end of P2 (FIFO: retires B(u+1)+A(u+1),
// leaves B(u+2)h0) before the barrier that precedes P3's next-tile reads.
// Grid: 1D, NXT*NYT (%8==0). M%256==0, N%256==0, K%64==0.
// =====================================================================
template<int OUT_BF16, int HAS_BIAS>
__global__ __launch_bounds__(512, 1) void gemm256(
    const bf16* __restrict__ A, const bf16* __restrict__ B, void* __restrict__ Cv,
    const float* __restrict__ bias, int K, int lda, int ldb, int ldc, int NXT)
{
  __shared__ bf16 As[2][256 * 32];
  __shared__ bf16 Bs[2][256 * 32];

  // XCD-bijective block swizzle (gridDim.x % 8 == 0)
  int nwg = gridDim.x, orig = blockIdx.x, cpx = nwg >> 3;
  int l = (orig & 7) * cpx + (orig >> 3);
  int tx = l % NXT, ty = l / NXT;
  long long rowBase = (long long)ty * 256;
  long long colBase = (long long)tx * 256;

  int tid = threadIdx.x, lane = tid & 63, wave = tid >> 6;
  int wr = wave >> 2, wc = wave & 3;       // 2x4 wave grid; wave tile 128x64
  int lrow = lane & 15, lslot = lane >> 4;
  int NT = K >> 5;                          // K-tiles of 32; NT even

  // ---- staging: chunk c = j*512+tid -> row r=c>>2, 16B slot sp=c&3;
  // source k-chunk = sp ^ ((r>>1)&3). j=0: rows 0-127, j=1: rows 128-255
  // ((r+128)>>1)&3 == (r>>1)&3, so one kc for both.
  int r0 = tid >> 2, sp = tid & 3;
  int kc0 = sp ^ ((r0 >> 1) & 3);
  const bf16* aQ0 = A + (rowBase + r0      ) * lda + kc0 * 8;
  const bf16* aQ1 = A + (rowBase + r0 + 128) * lda + kc0 * 8;
  const bf16* bQ0 = B + (colBase + r0      ) * ldb + kc0 * 8;
  const bf16* bQ1 = B + (colBase + r0 + 128) * ldb + kc0 * 8;
  int sdst = tid * 8;

  // dk = K-tile delta from loop anchor (compile-time 0..3), h = row-half
#define SGA(bs, dk, h) load_lds16((h ? aQ1 : aQ0) + (dk) * 32, &As[bs][sdst + (h) * 4096])
#define SGB(bs, dk, h) load_lds16((h ? bQ1 : bQ0) + (dk) * 32, &Bs[bs][sdst + (h) * 4096])

  // ---- fragment read bases: swizzle term (lslot ^ ((row>>1)&3)) is
  // m/n-independent since m*16,n*16,wr*128,wc*64 are 0 mod 8 in (row>>1)&3.
  int kOff = (lslot ^ ((lrow >> 1) & 3)) * 8;
  int aBase = (wr * 128 + lrow) * 32 + kOff;   // + m*512
  int bBase = (wc * 64 + lrow) * 32 + kOff;    // + n*512

#define RD_A(d0, d1, bs, m) do { \
    d0 = *(const s8v*)&As[bs][aBase + (m) * 512]; \
    d1 = *(const s8v*)&As[bs][aBase + ((m) + 1) * 512]; } while (0)
#define RD_B(arr, bs) do { \
    _Pragma("unroll") \
    for (int n_ = 0; n_ < 4; ++n_) arr[n_] = *(const s8v*)&Bs[bs][bBase + n_ * 512]; } while (0)

  f4v acc[8][4];
  #pragma unroll
  for (int m = 0; m < 8; ++m)
    #pragma unroll
    for (int n = 0; n < 4; ++n) acc[m][n] = {0.f, 0.f, 0.f, 0.f};

#define MMP(mp, A0, A1, BB) do { \
    __builtin_amdgcn_s_setprio(1); \
    _Pragma("unroll") \
    for (int n_ = 0; n_ < 4; ++n_) { \
      acc[mp][n_]       = __builtin_amdgcn_mfma_f32_16x16x32_bf16(A0, BB[n_], acc[mp][n_], 0, 0, 0); \
      acc[(mp) + 1][n_] = __builtin_amdgcn_mfma_f32_16x16x32_bf16(A1, BB[n_], acc[(mp) + 1][n_], 0, 0, 0); \
    } \
    __builtin_amdgcn_s_setprio(0); } while (0)

  s8v aX0, aX1, aY0, aY1;   // A m-pair sets (ping-pong per phase)
  s8v bX[4], bY[4];         // B sets (ping-pong per tile)

  // ---- prologue: A(0),B(0)->buf0 ; B(1)->Bs[1] ; gate ; first reads ----
  SGA(0, 0, 0); SGA(0, 0, 1);
  SGB(0, 0, 0); SGB(0, 0, 1);
  SGB(1, 1, 0); SGB(1, 1, 1);
  asm volatile("s_waitcnt vmcnt(2)" ::: "memory");   // A(0),B(0) landed
  __builtin_amdgcn_s_barrier();
  RD_B(bX, 0);
  RD_A(aX0, aX1, 0, 0);

  for (int u = 0; u < NT; u += 2) {
    bool st = (u + 2 < NT);
    // ================= tile u (buf 0) =================
    // P0: read m2,3 ; stage A(u+1)h0 ; MFMA m0,1 (aX,bX)
    RD_A(aY0, aY1, 0, 2);
    SGA(1, 1, 0);
    MMP(0, aX0, aX1, bX);
    __builtin_amdgcn_s_barrier();
    // P1: read m4,5 ; stage A(u+1)h1 ; MFMA m2,3
    RD_A(aX0, aX1, 0, 4);
    SGA(1, 1, 1);
    MMP(2, aY0, aY1, bX);
    __builtin_amdgcn_s_barrier();
    // P2: read m6,7 ; stage B(u+2)h0 ; MFMA m4,5 ; GATE
    RD_A(aY0, aY1, 0, 6);
    if (st) SGB(0, 2, 0);
    MMP(4, aX0, aX1, bX);
    if (st) asm volatile("s_waitcnt vmcnt(1)");
    else    asm volatile("s_waitcnt vmcnt(0)");
    __builtin_amdgcn_s_barrier();                    // gate: B(u+1),A(u+1) landed
    // P3: read B(u+1)->bY + A(u+1)m0,1->aX ; stage B(u+2)h1 ; MFMA m6,7
    RD_B(bY, 1);
    RD_A(aX0, aX1, 1, 0);
    if (st) SGB(0, 2, 1);
    MMP(6, aY0, aY1, bX);
    __builtin_amdgcn_s_barrier();
    // ================= tile u+1 (buf 1) =================
    // P0: read m2,3 ; stage A(u+2)h0 ; MFMA m0,1 (aX,bY)
    RD_A(aY0, aY1, 1, 2);
    if (st) SGA(0, 2, 0);
    MMP(0, aX0, aX1, bY);
    __builtin_amdgcn_s_barrier();
    // P1
    RD_A(aX0, aX1, 1, 4);
    if (st) SGA(0, 2, 1);
    MMP(2, aY0, aY1, bY);
    __builtin_amdgcn_s_barrier();
    // P2 (+gate)
    RD_A(aY0, aY1, 1, 6);
    if (st) SGB(1, 3, 0);
    MMP(4, aX0, aX1, bY);
    if (st) asm volatile("s_waitcnt vmcnt(1)");
    else    asm volatile("s_waitcnt vmcnt(0)");
    __builtin_amdgcn_s_barrier();                    // gate: B(u+2),A(u+2) landed
    // P3: read B(u+2)->bX + A(u+2)m0,1->aX (next iter) ; stage B(u+3)h1
    if (st) { RD_B(bX, 0); RD_A(aX0, aX1, 0, 0); }
    if (st) SGB(1, 3, 1);
    MMP(6, aY0, aY1, bY);
    __builtin_amdgcn_s_barrier();

    aQ0 += 64; aQ1 += 64; bQ0 += 64; bQ1 += 64;
  }
#undef SGA
#undef SGB
#undef RD_A
#undef RD_B
#undef MMP

  // epilogue: C/D layout col=lane&15, row=(lane>>4)*4+j
  float* Cf = (float*)Cv;
  bf16* Cb = (bf16*)Cv;
  int lcol = lane & 15, lr4 = (lane >> 4) * 4;
  #pragma unroll
  for (int m = 0; m < 8; ++m)
    #pragma unroll
    for (int n = 0; n < 4; ++n) {
      long long col = colBase + wc * 64 + n * 16 + lcol;
      float bv_ = HAS_BIAS ? bias[col] : 0.f;
      #pragma unroll
      for (int j = 0; j < 4; ++j) {
        long long row = rowBase + wr * 128 + m * 16 + lr4 + j;
        float v = acc[m][n][j] + bv_;
        if (OUT_BF16) Cb[row * ldc + col] = __float2bfloat16(v);
        else          Cf[row * ldc + col] = v;
      }
    }
}

// =====================================================================
// Generic 128-tile bf16 MFMA GEMM (small/odd shapes), bank-swizzled.
// =====================================================================
template<int BM, int BN, int WTM, int WTN, int OUT_BF16, int ADD_MODE, int HAS_BIAS>
__global__ __launch_bounds__(256) void gemm_bt(
    const bf16* __restrict__ A, const bf16* __restrict__ B, void* __restrict__ Cv,
    const float* __restrict__ bias, const void* __restrict__ addend,
    int K, int lda, int ldb, int ldc, int ldadd, int nz2,
    long long sA1, long long sA2, long long sB1, long long sB2,
    long long sC1, long long sC2, long long sD1, long long sD2)
{
  constexpr int BK = 32;
  constexpr int WM = BM / WTM, WN = BN / WTN;
  constexpr int FM = WM / 16, FN = WN / 16;
  static_assert(WTM * WTN == 4, "4 waves / 256 threads");
  static_assert((BM * BK) % 2048 == 0 && (BN * BK) % 2048 == 0, "staging coverage");
  __shared__ alignas(16) bf16 As[BM * BK];
  __shared__ alignas(16) bf16 Bs[BN * BK];

  int z = blockIdx.z;
  int z1 = z / nz2, z2 = z - z1 * nz2;
  A += z1 * sA1 + z2 * sA2;
  B += z1 * sB1 + z2 * sB2;
  long long coff = z1 * sC1 + z2 * sC2;
  long long doffz = z1 * sD1 + z2 * sD2;

  int tid = threadIdx.x;
  int lane = tid & 63, wave = tid >> 6;
  int wr = wave / WTN, wc = wave % WTN;
  int rowBase = blockIdx.y * BM;
  int colBase = blockIdx.x * BN;

  f4v acc[FM][FN];
  #pragma unroll
  for (int i = 0; i < FM; ++i)
    #pragma unroll
    for (int j = 0; j < FN; ++j) acc[i][j] = {0.f, 0.f, 0.f, 0.f};

  constexpr int A_LOADS = (BM * BK) / 2048;
  constexpr int B_LOADS = (BN * BK) / 2048;
  int lrow = lane & 15;
  int rsw = (lrow >> 1) & 3;
  int lkA = ((lane >> 4) ^ rsw) * 8;

  for (int k0 = 0; k0 < K; k0 += BK) {
    #pragma unroll
    for (int i = 0; i < A_LOADS; ++i) {
      int e = tid * 8 + i * 2048;
      int r_ = e >> 5, sp_ = (e >> 3) & 3, kc_ = sp_ ^ ((r_ >> 1) & 3);
      load_lds16(A + (long long)(rowBase + r_) * lda + k0 + (kc_ << 3), &As[e]);
    }
    #pragma unroll
    for (int i = 0; i < B_LOADS; ++i) {
      int e = tid * 8 + i * 2048;
      int r_ = e >> 5, sp_ = (e >> 3) & 3, kc_ = sp_ ^ ((r_ >> 1) & 3);
      load_lds16(B + (long long)(colBase + r_) * ldb + k0 + (kc_ << 3), &Bs[e]);
    }
    __syncthreads();

    s8v av[FM], bv[FN];
    #pragma unroll
    for (int fm = 0; fm < FM; ++fm)
      av[fm] = *(const s8v*)&As[(wr * WM + fm * 16 + lrow) * BK + lkA];
    #pragma unroll
    for (int fn = 0; fn < FN; ++fn)
      bv[fn] = *(const s8v*)&Bs[(wc * WN + fn * 16 + lrow) * BK + lkA];
    #pragma unroll
    for (int fm = 0; fm < FM; ++fm)
      #pragma unroll
      for (int fn = 0; fn < FN; ++fn)
        acc[fm][fn] = __builtin_amdgcn_mfma_f32_16x16x32_bf16(av[fm], bv[fn], acc[fm][fn], 0, 0, 0);
    __syncthreads();
  }

  bf16* Cb = (bf16*)Cv;
  float* Cf = (float*)Cv;
  const float* addf = (const float*)addend;
  const bf16* addb = (const bf16*)addend;
  int lcol = lane & 15, lr4 = (lane >> 4) * 4;
  #pragma unroll
  for (int fm = 0; fm < FM; ++fm) {
    #pragma unroll
    for (int fn = 0; fn < FN; ++fn) {
      int col = colBase + wc * WN + fn * 16 + lcol;
      #pragma unroll
      for (int j = 0; j < 4; ++j) {
        int row = rowBase + wr * WM + fm * 16 + lr4 + j;
        float v = acc[fm][fn][j];
        if (HAS_BIAS) v += bias[col];
        if (ADD_MODE == 1) v += addf[doffz + (long long)row * ldadd + col];
        if (ADD_MODE == 2) v += __bfloat162float(addb[doffz + (long long)row * ldadd + col]);
        long long idx = coff + (long long)row * ldc + col;
        if (OUT_BF16) Cb[idx] = __float2bfloat16(v);
        else          Cf[idx] = v;
      }
    }
  }
}

// ---------------- elementwise / helper kernels ----------------

__global__ void cast4(const float* __restrict__ in, bf16* __restrict__ out, int n4) {
  int i = blockIdx.x * 256 + threadIdx.x;
  if (i >= n4) return;
  float4 v = ((const float4*)in)[i];
  union { ushort4 u; bf16 h[4]; } o;
  o.h[0] = __float2bfloat16(v.x); o.h[1] = __float2bfloat16(v.y);
  o.h[2] = __float2bfloat16(v.z); o.h[3] = __float2bfloat16(v.w);
  ((ushort4*)out)[i] = o.u;
}

struct CastJobs {
  const float* s[8];
  bf16* d[8];
  int n4[8];
  int b0[8];
};
__global__ __launch_bounds__(256) void cast_multi(CastJobs J) {
  int blk = blockIdx.x, j = 0;
  #pragma unroll
  for (int k = 1; k < 8; ++k) if (blk >= J.b0[k]) j = k;
  int i = (blk - J.b0[j]) * 256 + threadIdx.x;
  if (i >= J.n4[j]) return;
  float4 v = ((const float4*)J.s[j])[i];
  union { ushort4 u; bf16 h[4]; } o;
  o.h[0] = __float2bfloat16(v.x); o.h[1] = __float2bfloat16(v.y);
  o.h[2] = __float2bfloat16(v.z); o.h[3] = __float2bfloat16(v.w);
  ((ushort4*)J.d[j])[i] = o.u;
}

// 32x32-tile bf16 transpose: in (R x C) -> out (C x R), batched over z
__global__ __launch_bounds__(256) void tr_bf16(const bf16* __restrict__ in, bf16* __restrict__ out,
                                               int R, int C) {
  __shared__ bf16 t[32][33];
  long long zo = (long long)blockIdx.z * R * C;
  int c0 = blockIdx.x * 32, r0 = blockIdx.y * 32;
  int tx = threadIdx.x & 31, ty = threadIdx.x >> 5;   // 32 x 8
  #pragma unroll
  for (int i = 0; i < 32; i += 8)
    t[ty + i][tx] = in[zo + (long long)(r0 + ty + i) * C + (c0 + tx)];
  __syncthreads();
  #pragma unroll
  for (int i = 0; i < 32; i += 8)
    out[zo + (long long)(c0 + ty + i) * R + (r0 + tx)] = t[tx][ty + i];
}

__device__ __forceinline__ float block_sum256(float v) {
  #pragma unroll
  for (int o = 32; o > 0; o >>= 1) v += __shfl_xor(v, o, 64);
  __shared__ float red[4];
  int lane = threadIdx.x & 63, w = threadIdx.x >> 6;
  if (lane == 0) red[w] = v;
  __syncthreads();
  return red[0] + red[1] + red[2] + red[3];
}

// fused-G1 row (stride 1088 fp32): [0:512) rmsnorm -> ckv ; [512:576) rope -> kr
__global__ __launch_bounds__(256) void rms_dkv(const float* __restrict__ dq,
    const float* __restrict__ w, const float* __restrict__ ch, const float* __restrict__ sh,
    bf16* __restrict__ ckv, bf16* __restrict__ kr) {
  int row = blockIdx.x, t = threadIdx.x;
  const float* xr = dq + (long long)row * 1088;
  float v0 = xr[t], v1 = xr[t + 256];
  float ss = block_sum256(v0 * v0 + v1 * v1);
  float sc = rsqrtf(ss * (1.0f / 512.0f) + 1.1920929e-07f);
  long long o = (long long)row * 512;
  ckv[o + t]       = __float2bfloat16(v0 * sc * w[t]);
  ckv[o + t + 256] = __float2bfloat16(v1 * sc * w[t + 256]);
  if (t < 64) {
    int s = row & (SEQ - 1);
    float a = xr[512 + t], r;
    if (t < 32) r = a * ch[s * 32 + t]      - xr[512 + t + 32] * sh[s * 32 + t];
    else        r = a * ch[s * 32 + t - 32] + xr[512 + t - 32] * sh[s * 32 + t - 32];
    kr[(long long)row * 64 + t] = __float2bfloat16(r);
  }
}

// fused-G1 row cols [576:1088) (stride 1088) : rmsnorm -> cq
__global__ __launch_bounds__(256) void rms512(const float* __restrict__ dq,
    const float* __restrict__ w, bf16* __restrict__ out) {
  int row = blockIdx.x, t = threadIdx.x;
  const float* xr = dq + (long long)row * 1088 + 576;
  float v0 = xr[t], v1 = xr[t + 256];
  float ss = block_sum256(v0 * v0 + v1 * v1);
  float sc = rsqrtf(ss * (1.0f / 512.0f) + 1.1920929e-07f);
  long long o = (long long)row * 512;
  out[o + t]       = __float2bfloat16(v0 * sc * w[t]);
  out[o + t + 256] = __float2bfloat16(v1 * sc * w[t + 256]);
}

__global__ void rope_qr(const float* __restrict__ in, const float* __restrict__ ch,
                        const float* __restrict__ sh, bf16* __restrict__ out) {
  int row = blockIdx.x, t = threadIdx.x;   // 64 threads
  const float* xr = in + (long long)row * 64;
  int s = row & (SEQ - 1);
  float a = xr[t], r;
  if (t < 32) r = a * ch[s * 32 + t]      - xr[t + 32] * sh[s * 32 + t];
  else        r = a * ch[s * 32 + t - 32] + xr[t - 32] * sh[s * 32 + t - 32];
  out[(long long)row * 64 + t] = __float2bfloat16(r);
}

// =====================================================================
extern "C" void kernel_launch(void* const* d_in, const int* in_sizes, int n_in,
                              void* d_out, int out_size, void* d_ws, size_t ws_size,
                              hipStream_t stream) {
  const float* x    = (const float*)d_in[0];
  const float* ch   = (const float*)d_in[1];
  const float* sh   = (const float*)d_in[2];
  const float* mask = (const float*)d_in[3];
  const float* wdkv = (const float*)d_in[4];
  const float* bdkv = (const float*)d_in[5];
  const float* kvnw = (const float*)d_in[6];
  const float* wdq  = (const float*)d_in[7];
  const float* bdq  = (const float*)d_in[8];
  const float* qnw  = (const float*)d_in[9];
  const float* wuq  = (const float*)d_in[10];
  const float* buq  = (const float*)d_in[11];
  const float* wqr  = (const float*)d_in[12];
  const float* bqr  = (const float*)d_in[13];
  const float* wuk  = (const float*)d_in[14];
  const float* wuv  = (const float*)d_in[15];
  const float* wo   = (const float*)d_in[16];
  const float* bo   = (const float*)d_in[17];
  float* out = (float*)d_out;
  (void)in_sizes; (void)n_in; (void)out_size; (void)ws_size;

  // ---------- workspace layout (total ~112 MB) ----------
  char* ws = (char*)d_ws;
  bf16* regionA = (bf16*)(ws);                       // 33,554,432 B : xb then wo_b
  bf16* outh    = (bf16*)(ws + 33554432);            // 33,554,432 B
  bf16* wdkv_b  = (bf16*)(ws + 67108864);            //  4,718,592 B  (576x4096)
  bf16* wdq_b   = (bf16*)(ws + 71827456);            //  4,194,304 B  (512x4096, adjacent -> cat)
  bf16* wuq_b   = (bf16*)(ws + 76021760);            //  4,194,304 B
  bf16* wqr_b   = (bf16*)(ws + 80216064);            //     65,536 B
  bf16* wuv_b   = (bf16*)(ws + 80281600);            //  4,194,304 B
  bf16* wuk_b   = (bf16*)(ws + 84475904);            //  4,194,304 B
  bf16* mask_b  = (bf16*)(ws + 88670208);            //  2,097,152 B
  char* regionB = ws + 90767360;                     // 20,971,520 B
  float* dq_cat = (float*)(regionB);                 // 17,825,792 B (phase 1: 4096x1088 fp32)
  bf16* Eb      = (bf16*)(regionB);                  // 16,777,216 B (phase 2)
  bf16* FT      = (bf16*)(regionB + 16777216);       //  4,194,304 B (phase 2)

  bf16* xb   = regionA;          // phase 1 of regionA
  bf16* wo_b = regionA;          // phase 2 of regionA (cast after G1c)

  // ---------- d_out used as scratch (64 MB); all dead before G13 ----------
  char* ob = (char*)d_out;
  bf16* qb     = (bf16*)(ob);                 // 33,554,432 B
  char* U      = ob + 33554432;
  bf16* ckv    = (bf16*)(U);                  // 4,194,304
  bf16* kr     = (bf16*)(U + 4194304);        //   524,288
  bf16* ckvT   = (bf16*)(U + 4718592);        // 4,194,304
  bf16* krT    = (bf16*)(U + 8912896);        //   524,288
  bf16* cq     = (bf16*)(U + 9437184);        // 4,194,304
  float* qr_pre= (float*)(U + 13631488);      // 1,048,576 (also hosts bias_cat before G4)
  bf16* qr_b   = (bf16*)(U + 14680064);       //   524,288
  bf16* Gm     = (bf16*)(U + 15204352);       // 2,097,152
  bf16* Mt     = (bf16*)(U + 17301504);       //   262,144
  bf16* base_b = (bf16*)(U + 17563648);       // 4,194,304

  float* bias_cat = qr_pre;   // 1088 floats; dead before G4 writes qr_pre

  long long Z = 0;

  // ---- fused early casts (8 jobs, 1 launch) ----
  {
    CastJobs J;
    const float* srcs[8] = {x, wdkv, wdq, wqr, mask, wuq, wuv, wuk};
    bf16* dsts[8] = {xb, wdkv_b, wdq_b, wqr_b, mask_b, wuq_b, wuv_b, wuk_b};
    int n4s[8] = {4194304, 589824, 524288, 8192, 262144, 524288, 524288, 524288};
    int accb = 0;
    for (int j = 0; j < 8; ++j) {
      J.s[j] = srcs[j]; J.d[j] = dsts[j]; J.n4[j] = n4s[j];
      J.b0[j] = accb; accb += (n4s[j] + 255) / 256;
    }
    cast_multi<<<dim3(accb), 256, 0, stream>>>(J);
  }
  // concatenated bias for fused G1+G2
  hipMemcpyAsync(bias_cat, bdkv, 576 * 4, hipMemcpyDeviceToDevice, stream);
  hipMemcpyAsync(bias_cat + 576, bdq, 512 * 4, hipMemcpyDeviceToDevice, stream);

  // G1c (fused G1+G2): dq_cat = x @ [wdkv;wdq]^T + [bdkv;bdq]  (4096 x 1088 x 4096), fp32
  gemm_bt<128, 64, 4, 1, 0, 0, 1><<<dim3(17, 32, 1), 256, 0, stream>>>(
      xb, wdkv_b, dq_cat, bias_cat, nullptr, 4096, 4096, 4096, 1088, 0, 1, Z,Z,Z,Z,Z,Z,Z,Z);
  rms_dkv<<<dim3(BT), 256, 0, stream>>>(dq_cat, kvnw, ch, sh, ckv, kr);
  rms512<<<dim3(BT), 256, 0, stream>>>(dq_cat, qnw, cq);
  tr_bf16<<<dim3(16, 32, 4), 256, 0, stream>>>(ckv, ckvT, 1024, 512);
  tr_bf16<<<dim3(2, 32, 4), 256, 0, stream>>>(kr, krT, 1024, 64);

  // ---- late cast (xb dead after G1c: regionA free for wo_b) ----
  cast4<<<dim3(16384), 256, 0, stream>>>(wo, wo_b, 4194304);

  // G3: q = cq @ wuq^T + b  (4096 x 4096 x 512), bf16 -> qb   [pipelined 256²]
  gemm256<1, 1><<<dim3(256), 512, 0, stream>>>(
      cq, wuq_b, qb, buq, 512, 512, 512, 4096, 16);

  // G4: qr_pre = cq @ wqr^T + b  (4096 x 64 x 512), fp32
  gemm_bt<128, 64, 4, 1, 0, 0, 1><<<dim3(1, 32, 1), 256, 0, stream>>>(
      cq, wqr_b, qr_pre, bqr, nullptr, 512, 512, 512, 64, 0, 1, Z,Z,Z,Z,Z,Z,Z,Z);
  rope_qr<<<dim3(BT), 64, 0, stream>>>(qr_pre, ch, sh, qr_b);

  // G6: G[b] = ckvT[b] @ ckvT[b]^T  (512 x 512 x 1024), z = b
  gemm_bt<128, 128, 2, 2, 1, 0, 0><<<dim3(4, 4, 4), 256, 0, stream>>>(
      ckvT, ckvT, Gm, nullptr, nullptr, 1024, 1024, 1024, 512, 0, 1,
      524288LL, Z, 524288LL, Z, 262144LL, Z, Z, Z);

  // G7: Mt[b] = ckvT[b] @ krT[b]^T  (512 x 64 x 1024), z = b
  gemm_bt<128, 64, 4, 1, 1, 0, 0><<<dim3(1, 4, 4), 256, 0, stream>>>(
      ckvT, krT, Mt, nullptr, nullptr, 1024, 1024, 1024, 64, 0, 1,
      524288LL, Z, 65536LL, Z, 32768LL, Z, Z, Z);

  // G8: base[b] = mask @ ckvT[b]^T  (1024 x 512 x 1024), z = b
  gemm_bt<128, 128, 2, 2, 1, 0, 0><<<dim3(4, 8, 4), 256, 0, stream>>>(
      mask_b, ckvT, base_b, nullptr, nullptr, 1024, 1024, 1024, 512, 0, 1,
      Z, Z, 524288LL, Z, 524288LL, Z, Z, Z);

  // G9: base[b] += qr[b] @ Mt[b]^T   (1024 x 512 x 64), in-place addend
  gemm_bt<128, 128, 2, 2, 1, 2, 0><<<dim3(4, 8, 4), 256, 0, stream>>>(
      qr_b, Mt, base_b, nullptr, base_b, 64, 64, 64, 512, 512, 1,
      65536LL, Z, 32768LL, Z, 524288LL, Z, 524288LL, Z);

  // G10: outh = base @ wuv^T  (4096 x 4096 x 512), bf16   [pipelined 256²]
  gemm256<1, 0><<<dim3(256), 512, 0, stream>>>(
      base_b, wuv_b, outh, nullptr, 512, 512, 512, 4096, 16);

  // E[b,h] = wuv_h @ G[b]^T  (128 x 512 x 512), z = (b,h)   (regionB phase 2)
  gemm_bt<128, 128, 2, 2, 1, 0, 0><<<dim3(4, 1, 128), 256, 0, stream>>>(
      wuv_b, Gm, Eb, nullptr, nullptr, 512, 512, 512, 512, 0, 32,
      Z, 65536LL, 262144LL, Z, 2097152LL, 65536LL, Z, Z);

  // FT[b,h] = E[b,h] @ wuk_h^T  (128 x 128 x 512), z = (b,h)
  gemm_bt<128, 128, 2, 2, 1, 0, 0><<<dim3(1, 1, 128), 256, 0, stream>>>(
      Eb, wuk_b, FT, nullptr, nullptr, 512, 512, 512, 128, 0, 32,
      2097152LL, 65536LL, Z, 65536LL, 524288LL, 16384LL, Z, Z);

  // G12: outh[b,:,h*128:+128] += qb[b,:,h*128:+128] @ FT[b,h]^T  (1024 x 128 x 128)
  gemm_bt<128, 128, 2, 2, 1, 2, 0><<<dim3(1, 8, 128), 256, 0, stream>>>(
      qb, FT, outh, nullptr, outh, 128, 4096, 128, 4096, 4096, 32,
      4194304LL, 128LL, 524288LL, 16384LL, 4194304LL, 128LL, 4194304LL, 128LL);

  // G13: out = outh @ wo^T + bo  (4096 x 4096 x 4096), fp32   [pipelined 256²]
  gemm256<0, 1><<<dim3(256), 512, 0, stream>>>(
      outh, wo_b, out, bo, 4096, 4096, 4096, 4096, 16);
}

// Round 12
// 439.999 us; speedup vs baseline: 1.0760x; 1.0760x over previous
//
#include <hip/hip_runtime.h>
#include <hip/hip_bf16.h>

typedef __attribute__((ext_vector_type(8))) short s8v;
typedef __attribute__((ext_vector_type(4))) float f4v;
typedef __hip_bfloat16 bf16;

// ---- problem constants ----
#define BSZ 4
#define SEQ 1024
#define IDIM 4096
#define RNK 512
#define RPD 64
#define NH 32
#define HD 128
#define BT 4096   // BSZ*SEQ tokens

__device__ __forceinline__ void load_lds16(const bf16* g, bf16* l) {
  __builtin_amdgcn_global_load_lds((const __attribute__((address_space(1))) void*)g,
                                   (__attribute__((address_space(3))) void*)l, 16, 0, 0);
}

// =====================================================================
// 256x256 8-wave bf16 GEMM — 8-phase, race-free stage map v3, soft barriers.
// (Best-known config from R8/R10: ~954 TF on 4096^3. FROZEN.)
// =====================================================================
template<int OUT_BF16, int HAS_BIAS>
__global__ __launch_bounds__(512, 2) void gemm256(
    const bf16* __restrict__ A, const bf16* __restrict__ B, void* __restrict__ Cv,
    const float* __restrict__ bias, int K, int lda, int ldb, int ldc, int NXT)
{
  __shared__ bf16 As[2][256 * 64];
  __shared__ bf16 Bs[2][256 * 64];

  // XCD-bijective block swizzle (gridDim.x % 8 == 0)
  int nwg = gridDim.x, orig = blockIdx.x, cpx = nwg >> 3;
  int l = (orig & 7) * cpx + (orig >> 3);
  int tx = l % NXT, ty = l / NXT;
  long long rowBase = (long long)ty * 256;
  long long colBase = (long long)tx * 256;

  int tid = threadIdx.x, lane = tid & 63, wave = tid >> 6;
  int wr = wave >> 2, wc = wave & 3;       // 2x4 wave grid; wave tile 128x64
  int lrow = lane & 15, lslot = lane >> 4;
  int NT = K >> 6;

  int srow = tid >> 3, sslot = tid & 7;
  int skc = sslot ^ (srow & 7);
  int sdst = srow * 64 + sslot * 8;
  const bf16* aP0 = A + (rowBase + srow      ) * lda + (skc << 3);
  const bf16* aP1 = A + (rowBase + srow +  64) * lda + (skc << 3);
  const bf16* aP2 = A + (rowBase + srow + 128) * lda + (skc << 3);
  const bf16* aP3 = A + (rowBase + srow + 192) * lda + (skc << 3);
  const bf16* bP0 = B + (colBase + srow      ) * ldb + (skc << 3);
  const bf16* bP1 = B + (colBase + srow +  64) * ldb + (skc << 3);
  const bf16* bP2 = B + (colBase + srow + 128) * ldb + (skc << 3);
  const bf16* bP3 = B + (colBase + srow + 192) * ldb + (skc << 3);

#define SG_A(bs, dk, i) load_lds16(aP##i + (dk) * 64, &As[bs][sdst + (i) * 4096])
#define SG_B(bs, dk, i) load_lds16(bP##i + (dk) * 64, &Bs[bs][sdst + (i) * 4096])

  int offk0 = ((lslot ^ (lrow & 7)) << 3);
  int offk1 = (((4 | lslot) ^ (lrow & 7)) << 3);
  int aoff = (wr * 128 + lrow) * 64;
  int boff = (wc * 64 + lrow) * 64;

  f4v acc[8][4];
  #pragma unroll
  for (int m = 0; m < 8; ++m)
    #pragma unroll
    for (int n = 0; n < 4; ++n) acc[m][n] = {0.f, 0.f, 0.f, 0.f};

#define PHASE(BSEL, Q, STG, GATE) do {                                         \
    const bf16* Ab_ = &As[BSEL][aoff];                                         \
    s8v a00 = *(const s8v*)(Ab_ + (2*(Q))   * 1024 + offk0);                   \
    s8v a01 = *(const s8v*)(Ab_ + (2*(Q))   * 1024 + offk1);                   \
    s8v a10 = *(const s8v*)(Ab_ + (2*(Q)+1) * 1024 + offk0);                   \
    s8v a11 = *(const s8v*)(Ab_ + (2*(Q)+1) * 1024 + offk1);                   \
    if ((Q) == 0) {                                                            \
      const bf16* Bb_ = &Bs[BSEL][boff];                                       \
      _Pragma("unroll")                                                        \
      for (int n = 0; n < 4; ++n) {                                            \
        b0[n] = *(const s8v*)(Bb_ + n * 1024 + offk0);                         \
        b1[n] = *(const s8v*)(Bb_ + n * 1024 + offk1);                         \
      }                                                                        \
    }                                                                          \
    STG;                                                                       \
    if ((Q) == 0) asm volatile("s_waitcnt lgkmcnt(8)");                        \
    __builtin_amdgcn_s_barrier();                                              \
    __builtin_amdgcn_s_setprio(1);                                             \
    _Pragma("unroll")                                                          \
    for (int n = 0; n < 4; ++n)                                                \
      acc[2*(Q)][n]   = __builtin_amdgcn_mfma_f32_16x16x32_bf16(a00, b0[n], acc[2*(Q)][n], 0, 0, 0);   \
    _Pragma("unroll")                                                          \
    for (int n = 0; n < 4; ++n)                                                \
      acc[2*(Q)+1][n] = __builtin_amdgcn_mfma_f32_16x16x32_bf16(a10, b0[n], acc[2*(Q)+1][n], 0, 0, 0); \
    _Pragma("unroll")                                                          \
    for (int n = 0; n < 4; ++n)                                                \
      acc[2*(Q)][n]   = __builtin_amdgcn_mfma_f32_16x16x32_bf16(a01, b1[n], acc[2*(Q)][n], 0, 0, 0);   \
    _Pragma("unroll")                                                          \
    for (int n = 0; n < 4; ++n)                                                \
      acc[2*(Q)+1][n] = __builtin_amdgcn_mfma_f32_16x16x32_bf16(a11, b1[n], acc[2*(Q)+1][n], 0, 0, 0); \
    __builtin_amdgcn_s_setprio(0);                                             \
    GATE;                                                                      \
    __builtin_amdgcn_s_barrier();                                              \
  } while (0)

  // ---- prologue
  SG_A(0, 0, 0); SG_A(0, 0, 1); SG_A(0, 0, 2); SG_A(0, 0, 3);
  SG_B(0, 0, 0); SG_B(0, 0, 1); SG_B(0, 0, 2); SG_B(0, 0, 3);
  SG_B(1, 1, 0); SG_B(1, 1, 1); SG_B(1, 1, 2); SG_B(1, 1, 3);
  asm volatile("s_waitcnt vmcnt(4)" ::: "memory");
  __builtin_amdgcn_s_barrier();

  for (int u = 0; u < NT; u += 2) {
    bool st = (u + 2 < NT);
    s8v b0[4], b1[4];
    // tile u (buf0)
    PHASE(0, 0, { SG_A(1, 1, 0); SG_A(1, 1, 1); }, {});
    PHASE(0, 1, { SG_A(1, 1, 2); SG_A(1, 1, 3); }, {});
    PHASE(0, 2, { if (st) { SG_B(0, 2, 0); SG_B(0, 2, 1); } }, {});
    PHASE(0, 3, { if (st) { SG_B(0, 2, 2); SG_B(0, 2, 3); } },
          { if (st) asm volatile("s_waitcnt vmcnt(4)" ::: "memory");
            else    asm volatile("s_waitcnt vmcnt(0)" ::: "memory"); });
    // tile u+1 (buf1)
    PHASE(1, 0, { if (st) { SG_A(0, 2, 0); SG_A(0, 2, 1); } }, {});
    PHASE(1, 1, { if (st) { SG_A(0, 2, 2); SG_A(0, 2, 3); } }, {});
    PHASE(1, 2, { if (st) { SG_B(1, 3, 0); SG_B(1, 3, 1); } }, {});
    PHASE(1, 3, { if (st) { SG_B(1, 3, 2); SG_B(1, 3, 3); } },
          { if (st) asm volatile("s_waitcnt vmcnt(4)" ::: "memory"); });
    aP0 += 128; aP1 += 128; aP2 += 128; aP3 += 128;
    bP0 += 128; bP1 += 128; bP2 += 128; bP3 += 128;
  }
#undef PHASE
#undef SG_A
#undef SG_B

  // epilogue: C/D layout col=lane&15, row=(lane>>4)*4+j
  float* Cf = (float*)Cv;
  bf16* Cb = (bf16*)Cv;
  int lcol = lane & 15, lr4 = (lane >> 4) * 4;
  #pragma unroll
  for (int m = 0; m < 8; ++m)
    #pragma unroll
    for (int n = 0; n < 4; ++n) {
      long long col = colBase + wc * 64 + n * 16 + lcol;
      float bv_ = HAS_BIAS ? bias[col] : 0.f;
      #pragma unroll
      for (int j = 0; j < 4; ++j) {
        long long row = rowBase + wr * 128 + m * 16 + lr4 + j;
        float v = acc[m][n][j] + bv_;
        if (OUT_BF16) Cb[row * ldc + col] = __float2bfloat16(v);
        else          Cf[row * ldc + col] = v;
      }
    }
}

// =====================================================================
// Generic 128-tile bf16 MFMA GEMM (small/odd shapes), bank-swizzled.
// =====================================================================
template<int BM, int BN, int WTM, int WTN, int OUT_BF16, int ADD_MODE, int HAS_BIAS>
__global__ __launch_bounds__(256) void gemm_bt(
    const bf16* __restrict__ A, const bf16* __restrict__ B, void* __restrict__ Cv,
    const float* __restrict__ bias, const void* __restrict__ addend,
    int K, int lda, int ldb, int ldc, int ldadd, int nz2,
    long long sA1, long long sA2, long long sB1, long long sB2,
    long long sC1, long long sC2, long long sD1, long long sD2)
{
  constexpr int BK = 32;
  constexpr int WM = BM / WTM, WN = BN / WTN;
  constexpr int FM = WM / 16, FN = WN / 16;
  static_assert(WTM * WTN == 4, "4 waves / 256 threads");
  static_assert((BM * BK) % 2048 == 0 && (BN * BK) % 2048 == 0, "staging coverage");
  __shared__ alignas(16) bf16 As[BM * BK];
  __shared__ alignas(16) bf16 Bs[BN * BK];

  int z = blockIdx.z;
  int z1 = z / nz2, z2 = z - z1 * nz2;
  A += z1 * sA1 + z2 * sA2;
  B += z1 * sB1 + z2 * sB2;
  long long coff = z1 * sC1 + z2 * sC2;
  long long doffz = z1 * sD1 + z2 * sD2;

  int tid = threadIdx.x;
  int lane = tid & 63, wave = tid >> 6;
  int wr = wave / WTN, wc = wave % WTN;
  int rowBase = blockIdx.y * BM;
  int colBase = blockIdx.x * BN;

  f4v acc[FM][FN];
  #pragma unroll
  for (int i = 0; i < FM; ++i)
    #pragma unroll
    for (int j = 0; j < FN; ++j) acc[i][j] = {0.f, 0.f, 0.f, 0.f};

  constexpr int A_LOADS = (BM * BK) / 2048;
  constexpr int B_LOADS = (BN * BK) / 2048;
  int lrow = lane & 15;
  int rsw = (lrow >> 1) & 3;
  int lkA = ((lane >> 4) ^ rsw) * 8;

  for (int k0 = 0; k0 < K; k0 += BK) {
    #pragma unroll
    for (int i = 0; i < A_LOADS; ++i) {
      int e = tid * 8 + i * 2048;
      int r_ = e >> 5, sp_ = (e >> 3) & 3, kc_ = sp_ ^ ((r_ >> 1) & 3);
      load_lds16(A + (long long)(rowBase + r_) * lda + k0 + (kc_ << 3), &As[e]);
    }
    #pragma unroll
    for (int i = 0; i < B_LOADS; ++i) {
      int e = tid * 8 + i * 2048;
      int r_ = e >> 5, sp_ = (e >> 3) & 3, kc_ = sp_ ^ ((r_ >> 1) & 3);
      load_lds16(B + (long long)(colBase + r_) * ldb + k0 + (kc_ << 3), &Bs[e]);
    }
    __syncthreads();

    s8v av[FM], bv[FN];
    #pragma unroll
    for (int fm = 0; fm < FM; ++fm)
      av[fm] = *(const s8v*)&As[(wr * WM + fm * 16 + lrow) * BK + lkA];
    #pragma unroll
    for (int fn = 0; fn < FN; ++fn)
      bv[fn] = *(const s8v*)&Bs[(wc * WN + fn * 16 + lrow) * BK + lkA];
    #pragma unroll
    for (int fm = 0; fm < FM; ++fm)
      #pragma unroll
      for (int fn = 0; fn < FN; ++fn)
        acc[fm][fn] = __builtin_amdgcn_mfma_f32_16x16x32_bf16(av[fm], bv[fn], acc[fm][fn], 0, 0, 0);
    __syncthreads();
  }

  bf16* Cb = (bf16*)Cv;
  float* Cf = (float*)Cv;
  const float* addf = (const float*)addend;
  const bf16* addb = (const bf16*)addend;
  int lcol = lane & 15, lr4 = (lane >> 4) * 4;
  #pragma unroll
  for (int fm = 0; fm < FM; ++fm) {
    #pragma unroll
    for (int fn = 0; fn < FN; ++fn) {
      int col = colBase + wc * WN + fn * 16 + lcol;
      #pragma unroll
      for (int j = 0; j < 4; ++j) {
        int row = rowBase + wr * WM + fm * 16 + lr4 + j;
        float v = acc[fm][fn][j];
        if (HAS_BIAS) v += bias[col];
        if (ADD_MODE == 1) v += addf[doffz + (long long)row * ldadd + col];
        if (ADD_MODE == 2) v += __bfloat162float(addb[doffz + (long long)row * ldadd + col]);
        long long idx = coff + (long long)row * ldc + col;
        if (OUT_BF16) Cb[idx] = __float2bfloat16(v);
        else          Cf[idx] = v;
      }
    }
  }
}

// ---------------- elementwise / helper kernels ----------------

__global__ void cast4(const float* __restrict__ in, bf16* __restrict__ out, int n4) {
  int i = blockIdx.x * 256 + threadIdx.x;
  if (i >= n4) return;
  float4 v = ((const float4*)in)[i];
  union { ushort4 u; bf16 h[4]; } o;
  o.h[0] = __float2bfloat16(v.x); o.h[1] = __float2bfloat16(v.y);
  o.h[2] = __float2bfloat16(v.z); o.h[3] = __float2bfloat16(v.w);
  ((ushort4*)out)[i] = o.u;
}

struct CastJobs {
  const float* s[8];
  bf16* d[8];
  int n4[8];
  int b0[8];
};
__global__ __launch_bounds__(256) void cast_multi(CastJobs J) {
  int blk = blockIdx.x, j = 0;
  #pragma unroll
  for (int k = 1; k < 8; ++k) if (blk >= J.b0[k]) j = k;
  int i = (blk - J.b0[j]) * 256 + threadIdx.x;
  if (i >= J.n4[j]) return;
  float4 v = ((const float4*)J.s[j])[i];
  union { ushort4 u; bf16 h[4]; } o;
  o.h[0] = __float2bfloat16(v.x); o.h[1] = __float2bfloat16(v.y);
  o.h[2] = __float2bfloat16(v.z); o.h[3] = __float2bfloat16(v.w);
  ((ushort4*)J.d[j])[i] = o.u;
}

// 32x32-tile bf16 transpose: in (R x C) -> out (C x R), batched over z
__global__ __launch_bounds__(256) void tr_bf16(const bf16* __restrict__ in, bf16* __restrict__ out,
                                               int R, int C) {
  __shared__ bf16 t[32][33];
  long long zo = (long long)blockIdx.z * R * C;
  int c0 = blockIdx.x * 32, r0 = blockIdx.y * 32;
  int tx = threadIdx.x & 31, ty = threadIdx.x >> 5;   // 32 x 8
  #pragma unroll
  for (int i = 0; i < 32; i += 8)
    t[ty + i][tx] = in[zo + (long long)(r0 + ty + i) * C + (c0 + tx)];
  __syncthreads();
  #pragma unroll
  for (int i = 0; i < 32; i += 8)
    out[zo + (long long)(c0 + ty + i) * R + (r0 + tx)] = t[tx][ty + i];
}

__device__ __forceinline__ float block_sum256(float v) {
  #pragma unroll
  for (int o = 32; o > 0; o >>= 1) v += __shfl_xor(v, o, 64);
  __shared__ float red[4];
  int lane = threadIdx.x & 63, w = threadIdx.x >> 6;
  if (lane == 0) red[w] = v;
  __syncthreads();
  return red[0] + red[1] + red[2] + red[3];
}

// fused-G1 row (stride 1088 fp32): [0:512) rmsnorm -> ckv ; [512:576) rope -> kr
__global__ __launch_bounds__(256) void rms_dkv(const float* __restrict__ dq,
    const float* __restrict__ w, const float* __restrict__ ch, const float* __restrict__ sh,
    bf16* __restrict__ ckv, bf16* __restrict__ kr) {
  int row = blockIdx.x, t = threadIdx.x;
  const float* xr = dq + (long long)row * 1088;
  float v0 = xr[t], v1 = xr[t + 256];
  float ss = block_sum256(v0 * v0 + v1 * v1);
  float sc = rsqrtf(ss * (1.0f / 512.0f) + 1.1920929e-07f);
  long long o = (long long)row * 512;
  ckv[o + t]       = __float2bfloat16(v0 * sc * w[t]);
  ckv[o + t + 256] = __float2bfloat16(v1 * sc * w[t + 256]);
  if (t < 64) {
    int s = row & (SEQ - 1);
    float a = xr[512 + t], r;
    if (t < 32) r = a * ch[s * 32 + t]      - xr[512 + t + 32] * sh[s * 32 + t];
    else        r = a * ch[s * 32 + t - 32] + xr[512 + t - 32] * sh[s * 32 + t - 32];
    kr[(long long)row * 64 + t] = __float2bfloat16(r);
  }
}

// fused-G1 row cols [576:1088) (stride 1088) : rmsnorm -> cq
__global__ __launch_bounds__(256) void rms512(const float* __restrict__ dq,
    const float* __restrict__ w, bf16* __restrict__ out) {
  int row = blockIdx.x, t = threadIdx.x;
  const float* xr = dq + (long long)row * 1088 + 576;
  float v0 = xr[t], v1 = xr[t + 256];
  float ss = block_sum256(v0 * v0 + v1 * v1);
  float sc = rsqrtf(ss * (1.0f / 512.0f) + 1.1920929e-07f);
  long long o = (long long)row * 512;
  out[o + t]       = __float2bfloat16(v0 * sc * w[t]);
  out[o + t + 256] = __float2bfloat16(v1 * sc * w[t + 256]);
}

__global__ void rope_qr(const float* __restrict__ in, const float* __restrict__ ch,
                        const float* __restrict__ sh, bf16* __restrict__ out) {
  int row = blockIdx.x, t = threadIdx.x;   // 64 threads
  const float* xr = in + (long long)row * 64;
  int s = row & (SEQ - 1);
  float a = xr[t], r;
  if (t < 32) r = a * ch[s * 32 + t]      - xr[t + 32] * sh[s * 32 + t];
  else        r = a * ch[s * 32 + t - 32] + xr[t - 32] * sh[s * 32 + t - 32];
  out[(long long)row * 64 + t] = __float2bfloat16(r);
}

// =====================================================================
extern "C" void kernel_launch(void* const* d_in, const int* in_sizes, int n_in,
                              void* d_out, int out_size, void* d_ws, size_t ws_size,
                              hipStream_t stream) {
  const float* x    = (const float*)d_in[0];
  const float* ch   = (const float*)d_in[1];
  const float* sh   = (const float*)d_in[2];
  const float* mask = (const float*)d_in[3];
  const float* wdkv = (const float*)d_in[4];
  const float* bdkv = (const float*)d_in[5];
  const float* kvnw = (const float*)d_in[6];
  const float* wdq  = (const float*)d_in[7];
  const float* bdq  = (const float*)d_in[8];
  const float* qnw  = (const float*)d_in[9];
  const float* wuq  = (const float*)d_in[10];
  const float* buq  = (const float*)d_in[11];
  const float* wqr  = (const float*)d_in[12];
  const float* bqr  = (const float*)d_in[13];
  const float* wuk  = (const float*)d_in[14];
  const float* wuv  = (const float*)d_in[15];
  const float* wo   = (const float*)d_in[16];
  const float* bo   = (const float*)d_in[17];
  float* out = (float*)d_out;
  (void)in_sizes; (void)n_in; (void)out_size; (void)ws_size;

  // ---------- workspace layout (total ~112 MB) ----------
  char* ws = (char*)d_ws;
  bf16* regionA = (bf16*)(ws);                       // 33,554,432 B : xb then wo_b
  bf16* outh    = (bf16*)(ws + 33554432);            // 33,554,432 B
  bf16* wdkv_b  = (bf16*)(ws + 67108864);            //  4,718,592 B  (576x4096)
  bf16* wdq_b   = (bf16*)(ws + 71827456);            //  4,194,304 B  (512x4096, adjacent -> cat)
  bf16* wuq_b   = (bf16*)(ws + 76021760);            //  4,194,304 B
  bf16* wqr_b   = (bf16*)(ws + 80216064);            //     65,536 B
  bf16* wuv_b   = (bf16*)(ws + 80281600);            //  4,194,304 B
  bf16* wuk_b   = (bf16*)(ws + 84475904);            //  4,194,304 B
  bf16* mask_b  = (bf16*)(ws + 88670208);            //  2,097,152 B
  char* regionB = ws + 90767360;                     // 20,971,520 B
  float* dq_cat = (float*)(regionB);                 // 17,825,792 B (phase 1: 4096x1088 fp32)
  bf16* Eb      = (bf16*)(regionB);                  // 16,777,216 B (phase 2)
  bf16* FT      = (bf16*)(regionB + 16777216);       //  4,194,304 B (phase 2)

  bf16* xb   = regionA;          // phase 1 of regionA
  bf16* wo_b = regionA;          // phase 2 of regionA (cast after G1c)

  // ---------- d_out used as scratch (64 MB); all dead before G13 ----------
  char* ob = (char*)d_out;
  bf16* qb     = (bf16*)(ob);                 // 33,554,432 B
  char* U      = ob + 33554432;
  bf16* ckv    = (bf16*)(U);                  // 4,194,304
  bf16* kr     = (bf16*)(U + 4194304);        //   524,288
  bf16* ckvT   = (bf16*)(U + 4718592);        // 4,194,304
  bf16* krT    = (bf16*)(U + 8912896);        //   524,288
  bf16* cq     = (bf16*)(U + 9437184);        // 4,194,304
  float* qr_pre= (float*)(U + 13631488);      // 1,048,576 (also hosts bias_cat before G4)
  bf16* qr_b   = (bf16*)(U + 14680064);       //   524,288
  bf16* Gm     = (bf16*)(U + 15204352);       // 2,097,152
  bf16* Mt     = (bf16*)(U + 17301504);       //   262,144
  bf16* base_b = (bf16*)(U + 17563648);       // 4,194,304

  float* bias_cat = qr_pre;   // 1088 floats; dead before G4 writes qr_pre

  long long Z = 0;

  // ---- fused early casts (8 jobs, 1 launch) ----
  {
    CastJobs J;
    const float* srcs[8] = {x, wdkv, wdq, wqr, mask, wuq, wuv, wuk};
    bf16* dsts[8] = {xb, wdkv_b, wdq_b, wqr_b, mask_b, wuq_b, wuv_b, wuk_b};
    int n4s[8] = {4194304, 589824, 524288, 8192, 262144, 524288, 524288, 524288};
    int accb = 0;
    for (int j = 0; j < 8; ++j) {
      J.s[j] = srcs[j]; J.d[j] = dsts[j]; J.n4[j] = n4s[j];
      J.b0[j] = accb; accb += (n4s[j] + 255) / 256;
    }
    cast_multi<<<dim3(accb), 256, 0, stream>>>(J);
  }
  // concatenated bias for fused G1+G2
  hipMemcpyAsync(bias_cat, bdkv, 576 * 4, hipMemcpyDeviceToDevice, stream);
  hipMemcpyAsync(bias_cat + 576, bdq, 512 * 4, hipMemcpyDeviceToDevice, stream);

  // G1c (fused G1+G2): dq_cat = x @ [wdkv;wdq]^T + [bdkv;bdq]  (4096 x 1088 x 4096), fp32
  gemm_bt<128, 64, 4, 1, 0, 0, 1><<<dim3(17, 32, 1), 256, 0, stream>>>(
      xb, wdkv_b, dq_cat, bias_cat, nullptr, 4096, 4096, 4096, 1088, 0, 1, Z,Z,Z,Z,Z,Z,Z,Z);
  rms_dkv<<<dim3(BT), 256, 0, stream>>>(dq_cat, kvnw, ch, sh, ckv, kr);
  rms512<<<dim3(BT), 256, 0, stream>>>(dq_cat, qnw, cq);
  tr_bf16<<<dim3(16, 32, 4), 256, 0, stream>>>(ckv, ckvT, 1024, 512);
  tr_bf16<<<dim3(2, 32, 4), 256, 0, stream>>>(kr, krT, 1024, 64);

  // ---- late cast (xb dead after G1c: regionA free for wo_b) ----
  cast4<<<dim3(16384), 256, 0, stream>>>(wo, wo_b, 4194304);

  // G3: q = cq @ wuq^T + b  (4096 x 4096 x 512), bf16 -> qb   [8-phase 256²]
  gemm256<1, 1><<<dim3(256), 512, 0, stream>>>(
      cq, wuq_b, qb, buq, 512, 512, 512, 4096, 16);

  // G4: qr_pre = cq @ wqr^T + b  (4096 x 64 x 512), fp32
  gemm_bt<128, 64, 4, 1, 0, 0, 1><<<dim3(1, 32, 1), 256, 0, stream>>>(
      cq, wqr_b, qr_pre, bqr, nullptr, 512, 512, 512, 64, 0, 1, Z,Z,Z,Z,Z,Z,Z,Z);
  rope_qr<<<dim3(BT), 64, 0, stream>>>(qr_pre, ch, sh, qr_b);

  // G6: G[b] = ckvT[b] @ ckvT[b]^T  (512 x 512 x 1024), z = b   [BN=64: 128 blocks]
  gemm_bt<128, 64, 4, 1, 1, 0, 0><<<dim3(8, 4, 4), 256, 0, stream>>>(
      ckvT, ckvT, Gm, nullptr, nullptr, 1024, 1024, 1024, 512, 0, 1,
      524288LL, Z, 524288LL, Z, 262144LL, Z, Z, Z);

  // G7: Mt[b] = ckvT[b] @ krT[b]^T  (512 x 64 x 1024), z = b   [BM=64: 32 blocks]
  gemm_bt<64, 64, 2, 2, 1, 0, 0><<<dim3(1, 8, 4), 256, 0, stream>>>(
      ckvT, krT, Mt, nullptr, nullptr, 1024, 1024, 1024, 64, 0, 1,
      524288LL, Z, 65536LL, Z, 32768LL, Z, Z, Z);

  // G8: base[b] = mask @ ckvT[b]^T  (1024 x 512 x 1024), z = b   [BN=64: 256 blocks]
  gemm_bt<128, 64, 4, 1, 1, 0, 0><<<dim3(8, 8, 4), 256, 0, stream>>>(
      mask_b, ckvT, base_b, nullptr, nullptr, 1024, 1024, 1024, 512, 0, 1,
      Z, Z, 524288LL, Z, 524288LL, Z, Z, Z);

  // G9: base[b] += qr[b] @ Mt[b]^T   (1024 x 512 x 64), in-place addend [BN=64: 256 blocks]
  gemm_bt<128, 64, 4, 1, 1, 2, 0><<<dim3(8, 8, 4), 256, 0, stream>>>(
      qr_b, Mt, base_b, nullptr, base_b, 64, 64, 64, 512, 512, 1,
      65536LL, Z, 32768LL, Z, 524288LL, Z, 524288LL, Z);

  // G10: outh = base @ wuv^T  (4096 x 4096 x 512), bf16   [8-phase 256²]
  gemm256<1, 0><<<dim3(256), 512, 0, stream>>>(
      base_b, wuv_b, outh, nullptr, 512, 512, 512, 4096, 16);

  // E[b,h] = wuv_h @ G[b]^T  (128 x 512 x 512), z = (b,h)   (regionB phase 2)
  gemm_bt<128, 128, 2, 2, 1, 0, 0><<<dim3(4, 1, 128), 256, 0, stream>>>(
      wuv_b, Gm, Eb, nullptr, nullptr, 512, 512, 512, 512, 0, 32,
      Z, 65536LL, 262144LL, Z, 2097152LL, 65536LL, Z, Z);

  // FT[b,h] = E[b,h] @ wuk_h^T  (128 x 128 x 512), z = (b,h)   [BN=64: 256 blocks]
  gemm_bt<128, 64, 4, 1, 1, 0, 0><<<dim3(2, 1, 128), 256, 0, stream>>>(
      Eb, wuk_b, FT, nullptr, nullptr, 512, 512, 512, 128, 0, 32,
      2097152LL, 65536LL, Z, 65536LL, 524288LL, 16384LL, Z, Z);

  // G12: outh[b,:,h*128:+128] += qb[b,:,h*128:+128] @ FT[b,h]^T  (1024 x 128 x 128)
  gemm_bt<128, 128, 2, 2, 1, 2, 0><<<dim3(1, 8, 128), 256, 0, stream>>>(
      qb, FT, outh, nullptr, outh, 128, 4096, 128, 4096, 4096, 32,
      4194304LL, 128LL, 524288LL, 16384LL, 4194304LL, 128LL, 4194304LL, 128LL);

  // G13: out = outh @ wo^T + bo  (4096 x 4096 x 4096), fp32   [8-phase 256²]
  gemm256<0, 1><<<dim3(256), 512, 0, stream>>>(
      outh, wo_b, out, bo, 4096, 4096, 4096, 4096, 16);
}

// Round 13
// 420.336 us; speedup vs baseline: 1.1264x; 1.0468x over previous
//
#include <hip/hip_runtime.h>
#include <hip/hip_bf16.h>

typedef __attribute__((ext_vector_type(8))) short s8v;
typedef __attribute__((ext_vector_type(4))) float f4v;
typedef __hip_bfloat16 bf16;

// ---- problem constants ----
#define BSZ 4
#define SEQ 1024
#define IDIM 4096
#define RNK 512
#define RPD 64
#define NH 32
#define HD 128
#define BT 4096   // BSZ*SEQ tokens

__device__ __forceinline__ void load_lds16(const bf16* g, bf16* l) {
  __builtin_amdgcn_global_load_lds((const __attribute__((address_space(1))) void*)g,
                                   (__attribute__((address_space(3))) void*)l, 16, 0, 0);
}

// =====================================================================
// 256x256 8-wave bf16 GEMM — 8-phase, race-free stage map v3, soft barriers.
// (Best-known config from R8/R10: ~954 TF on 4096^3. FROZEN.)
// =====================================================================
template<int OUT_BF16, int HAS_BIAS>
__global__ __launch_bounds__(512, 2) void gemm256(
    const bf16* __restrict__ A, const bf16* __restrict__ B, void* __restrict__ Cv,
    const float* __restrict__ bias, int K, int lda, int ldb, int ldc, int NXT)
{
  __shared__ bf16 As[2][256 * 64];
  __shared__ bf16 Bs[2][256 * 64];

  // XCD-bijective block swizzle (gridDim.x % 8 == 0)
  int nwg = gridDim.x, orig = blockIdx.x, cpx = nwg >> 3;
  int l = (orig & 7) * cpx + (orig >> 3);
  int tx = l % NXT, ty = l / NXT;
  long long rowBase = (long long)ty * 256;
  long long colBase = (long long)tx * 256;

  int tid = threadIdx.x, lane = tid & 63, wave = tid >> 6;
  int wr = wave >> 2, wc = wave & 3;       // 2x4 wave grid; wave tile 128x64
  int lrow = lane & 15, lslot = lane >> 4;
  int NT = K >> 6;

  int srow = tid >> 3, sslot = tid & 7;
  int skc = sslot ^ (srow & 7);
  int sdst = srow * 64 + sslot * 8;
  const bf16* aP0 = A + (rowBase + srow      ) * lda + (skc << 3);
  const bf16* aP1 = A + (rowBase + srow +  64) * lda + (skc << 3);
  const bf16* aP2 = A + (rowBase + srow + 128) * lda + (skc << 3);
  const bf16* aP3 = A + (rowBase + srow + 192) * lda + (skc << 3);
  const bf16* bP0 = B + (colBase + srow      ) * ldb + (skc << 3);
  const bf16* bP1 = B + (colBase + srow +  64) * ldb + (skc << 3);
  const bf16* bP2 = B + (colBase + srow + 128) * ldb + (skc << 3);
  const bf16* bP3 = B + (colBase + srow + 192) * ldb + (skc << 3);

#define SG_A(bs, dk, i) load_lds16(aP##i + (dk) * 64, &As[bs][sdst + (i) * 4096])
#define SG_B(bs, dk, i) load_lds16(bP##i + (dk) * 64, &Bs[bs][sdst + (i) * 4096])

  int offk0 = ((lslot ^ (lrow & 7)) << 3);
  int offk1 = (((4 | lslot) ^ (lrow & 7)) << 3);
  int aoff = (wr * 128 + lrow) * 64;
  int boff = (wc * 64 + lrow) * 64;

  f4v acc[8][4];
  #pragma unroll
  for (int m = 0; m < 8; ++m)
    #pragma unroll
    for (int n = 0; n < 4; ++n) acc[m][n] = {0.f, 0.f, 0.f, 0.f};

#define PHASE(BSEL, Q, STG, GATE) do {                                         \
    const bf16* Ab_ = &As[BSEL][aoff];                                         \
    s8v a00 = *(const s8v*)(Ab_ + (2*(Q))   * 1024 + offk0);                   \
    s8v a01 = *(const s8v*)(Ab_ + (2*(Q))   * 1024 + offk1);                   \
    s8v a10 = *(const s8v*)(Ab_ + (2*(Q)+1) * 1024 + offk0);                   \
    s8v a11 = *(const s8v*)(Ab_ + (2*(Q)+1) * 1024 + offk1);                   \
    if ((Q) == 0) {                                                            \
      const bf16* Bb_ = &Bs[BSEL][boff];                                       \
      _Pragma("unroll")                                                        \
      for (int n = 0; n < 4; ++n) {                                            \
        b0[n] = *(const s8v*)(Bb_ + n * 1024 + offk0);                         \
        b1[n] = *(const s8v*)(Bb_ + n * 1024 + offk1);                         \
      }                                                                        \
    }                                                                          \
    STG;                                                                       \
    if ((Q) == 0) asm volatile("s_waitcnt lgkmcnt(8)");                        \
    __builtin_amdgcn_s_barrier();                                              \
    __builtin_amdgcn_s_setprio(1);                                             \
    _Pragma("unroll")                                                          \
    for (int n = 0; n < 4; ++n)                                                \
      acc[2*(Q)][n]   = __builtin_amdgcn_mfma_f32_16x16x32_bf16(a00, b0[n], acc[2*(Q)][n], 0, 0, 0);   \
    _Pragma("unroll")                                                          \
    for (int n = 0; n < 4; ++n)                                                \
      acc[2*(Q)+1][n] = __builtin_amdgcn_mfma_f32_16x16x32_bf16(a10, b0[n], acc[2*(Q)+1][n], 0, 0, 0); \
    _Pragma("unroll")                                                          \
    for (int n = 0; n < 4; ++n)                                                \
      acc[2*(Q)][n]   = __builtin_amdgcn_mfma_f32_16x16x32_bf16(a01, b1[n], acc[2*(Q)][n], 0, 0, 0);   \
    _Pragma("unroll")                                                          \
    for (int n = 0; n < 4; ++n)                                                \
      acc[2*(Q)+1][n] = __builtin_amdgcn_mfma_f32_16x16x32_bf16(a11, b1[n], acc[2*(Q)+1][n], 0, 0, 0); \
    __builtin_amdgcn_s_setprio(0);                                             \
    GATE;                                                                      \
    __builtin_amdgcn_s_barrier();                                              \
  } while (0)

  // ---- prologue
  SG_A(0, 0, 0); SG_A(0, 0, 1); SG_A(0, 0, 2); SG_A(0, 0, 3);
  SG_B(0, 0, 0); SG_B(0, 0, 1); SG_B(0, 0, 2); SG_B(0, 0, 3);
  SG_B(1, 1, 0); SG_B(1, 1, 1); SG_B(1, 1, 2); SG_B(1, 1, 3);
  asm volatile("s_waitcnt vmcnt(4)" ::: "memory");
  __builtin_amdgcn_s_barrier();

  for (int u = 0; u < NT; u += 2) {
    bool st = (u + 2 < NT);
    s8v b0[4], b1[4];
    // tile u (buf0)
    PHASE(0, 0, { SG_A(1, 1, 0); SG_A(1, 1, 1); }, {});
    PHASE(0, 1, { SG_A(1, 1, 2); SG_A(1, 1, 3); }, {});
    PHASE(0, 2, { if (st) { SG_B(0, 2, 0); SG_B(0, 2, 1); } }, {});
    PHASE(0, 3, { if (st) { SG_B(0, 2, 2); SG_B(0, 2, 3); } },
          { if (st) asm volatile("s_waitcnt vmcnt(4)" ::: "memory");
            else    asm volatile("s_waitcnt vmcnt(0)" ::: "memory"); });
    // tile u+1 (buf1)
    PHASE(1, 0, { if (st) { SG_A(0, 2, 0); SG_A(0, 2, 1); } }, {});
    PHASE(1, 1, { if (st) { SG_A(0, 2, 2); SG_A(0, 2, 3); } }, {});
    PHASE(1, 2, { if (st) { SG_B(1, 3, 0); SG_B(1, 3, 1); } }, {});
    PHASE(1, 3, { if (st) { SG_B(1, 3, 2); SG_B(1, 3, 3); } },
          { if (st) asm volatile("s_waitcnt vmcnt(4)" ::: "memory"); });
    aP0 += 128; aP1 += 128; aP2 += 128; aP3 += 128;
    bP0 += 128; bP1 += 128; bP2 += 128; bP3 += 128;
  }
#undef PHASE
#undef SG_A
#undef SG_B

  // epilogue: C/D layout col=lane&15, row=(lane>>4)*4+j
  float* Cf = (float*)Cv;
  bf16* Cb = (bf16*)Cv;
  int lcol = lane & 15, lr4 = (lane >> 4) * 4;
  #pragma unroll
  for (int m = 0; m < 8; ++m)
    #pragma unroll
    for (int n = 0; n < 4; ++n) {
      long long col = colBase + wc * 64 + n * 16 + lcol;
      float bv_ = HAS_BIAS ? bias[col] : 0.f;
      #pragma unroll
      for (int j = 0; j < 4; ++j) {
        long long row = rowBase + wr * 128 + m * 16 + lr4 + j;
        float v = acc[m][n][j] + bv_;
        if (OUT_BF16) Cb[row * ldc + col] = __float2bfloat16(v);
        else          Cf[row * ldc + col] = v;
      }
    }
}

// =====================================================================
// Generic 128-tile bf16 MFMA GEMM (small/odd shapes), bank-swizzled.
// =====================================================================
template<int BM, int BN, int WTM, int WTN, int OUT_BF16, int ADD_MODE, int HAS_BIAS>
__global__ __launch_bounds__(256) void gemm_bt(
    const bf16* __restrict__ A, const bf16* __restrict__ B, void* __restrict__ Cv,
    const float* __restrict__ bias, const void* __restrict__ addend,
    int K, int lda, int ldb, int ldc, int ldadd, int nz2,
    long long sA1, long long sA2, long long sB1, long long sB2,
    long long sC1, long long sC2, long long sD1, long long sD2)
{
  constexpr int BK = 32;
  constexpr int WM = BM / WTM, WN = BN / WTN;
  constexpr int FM = WM / 16, FN = WN / 16;
  static_assert(WTM * WTN == 4, "4 waves / 256 threads");
  static_assert((BM * BK) % 2048 == 0 && (BN * BK) % 2048 == 0, "staging coverage");
  __shared__ alignas(16) bf16 As[BM * BK];
  __shared__ alignas(16) bf16 Bs[BN * BK];

  int z = blockIdx.z;
  int z1 = z / nz2, z2 = z - z1 * nz2;
  A += z1 * sA1 + z2 * sA2;
  B += z1 * sB1 + z2 * sB2;
  long long coff = z1 * sC1 + z2 * sC2;
  long long doffz = z1 * sD1 + z2 * sD2;

  int tid = threadIdx.x;
  int lane = tid & 63, wave = tid >> 6;
  int wr = wave / WTN, wc = wave % WTN;
  int rowBase = blockIdx.y * BM;
  int colBase = blockIdx.x * BN;

  f4v acc[FM][FN];
  #pragma unroll
  for (int i = 0; i < FM; ++i)
    #pragma unroll
    for (int j = 0; j < FN; ++j) acc[i][j] = {0.f, 0.f, 0.f, 0.f};

  constexpr int A_LOADS = (BM * BK) / 2048;
  constexpr int B_LOADS = (BN * BK) / 2048;
  int lrow = lane & 15;
  int rsw = (lrow >> 1) & 3;
  int lkA = ((lane >> 4) ^ rsw) * 8;

  for (int k0 = 0; k0 < K; k0 += BK) {
    #pragma unroll
    for (int i = 0; i < A_LOADS; ++i) {
      int e = tid * 8 + i * 2048;
      int r_ = e >> 5, sp_ = (e >> 3) & 3, kc_ = sp_ ^ ((r_ >> 1) & 3);
      load_lds16(A + (long long)(rowBase + r_) * lda + k0 + (kc_ << 3), &As[e]);
    }
    #pragma unroll
    for (int i = 0; i < B_LOADS; ++i) {
      int e = tid * 8 + i * 2048;
      int r_ = e >> 5, sp_ = (e >> 3) & 3, kc_ = sp_ ^ ((r_ >> 1) & 3);
      load_lds16(B + (long long)(colBase + r_) * ldb + k0 + (kc_ << 3), &Bs[e]);
    }
    __syncthreads();

    s8v av[FM], bv[FN];
    #pragma unroll
    for (int fm = 0; fm < FM; ++fm)
      av[fm] = *(const s8v*)&As[(wr * WM + fm * 16 + lrow) * BK + lkA];
    #pragma unroll
    for (int fn = 0; fn < FN; ++fn)
      bv[fn] = *(const s8v*)&Bs[(wc * WN + fn * 16 + lrow) * BK + lkA];
    #pragma unroll
    for (int fm = 0; fm < FM; ++fm)
      #pragma unroll
      for (int fn = 0; fn < FN; ++fn)
        acc[fm][fn] = __builtin_amdgcn_mfma_f32_16x16x32_bf16(av[fm], bv[fn], acc[fm][fn], 0, 0, 0);
    __syncthreads();
  }

  bf16* Cb = (bf16*)Cv;
  float* Cf = (float*)Cv;
  const float* addf = (const float*)addend;
  const bf16* addb = (const bf16*)addend;
  int lcol = lane & 15, lr4 = (lane >> 4) * 4;
  #pragma unroll
  for (int fm = 0; fm < FM; ++fm) {
    #pragma unroll
    for (int fn = 0; fn < FN; ++fn) {
      int col = colBase + wc * WN + fn * 16 + lcol;
      #pragma unroll
      for (int j = 0; j < 4; ++j) {
        int row = rowBase + wr * WM + fm * 16 + lr4 + j;
        float v = acc[fm][fn][j];
        if (HAS_BIAS) v += bias[col];
        if (ADD_MODE == 1) v += addf[doffz + (long long)row * ldadd + col];
        if (ADD_MODE == 2) v += __bfloat162float(addb[doffz + (long long)row * ldadd + col]);
        long long idx = coff + (long long)row * ldc + col;
        if (OUT_BF16) Cb[idx] = __float2bfloat16(v);
        else          Cf[idx] = v;
      }
    }
  }
}

// ---------------- elementwise / helper kernels ----------------

__global__ void cast4(const float* __restrict__ in, bf16* __restrict__ out, int n4) {
  int i = blockIdx.x * 256 + threadIdx.x;
  if (i >= n4) return;
  float4 v = ((const float4*)in)[i];
  union { ushort4 u; bf16 h[4]; } o;
  o.h[0] = __float2bfloat16(v.x); o.h[1] = __float2bfloat16(v.y);
  o.h[2] = __float2bfloat16(v.z); o.h[3] = __float2bfloat16(v.w);
  ((ushort4*)out)[i] = o.u;
}

struct CastJobs {
  const float* s[8];
  bf16* d[8];
  int n4[8];
  int b0[8];
};
__global__ __launch_bounds__(256) void cast_multi(CastJobs J) {
  int blk = blockIdx.x, j = 0;
  #pragma unroll
  for (int k = 1; k < 8; ++k) if (blk >= J.b0[k]) j = k;
  int i = (blk - J.b0[j]) * 256 + threadIdx.x;
  if (i >= J.n4[j]) return;
  float4 v = ((const float4*)J.s[j])[i];
  union { ushort4 u; bf16 h[4]; } o;
  o.h[0] = __float2bfloat16(v.x); o.h[1] = __float2bfloat16(v.y);
  o.h[2] = __float2bfloat16(v.z); o.h[3] = __float2bfloat16(v.w);
  ((ushort4*)J.d[j])[i] = o.u;
}

// combined transpose into ckvT_ext (b, 576, 1024):
// rows 0-511  <- ckv (b,1024,512)^T ; rows 512-575 <- kr (b,1024,64)^T
__global__ __launch_bounds__(256) void tr_ckv(const bf16* __restrict__ ckv,
                                              const bf16* __restrict__ kr,
                                              bf16* __restrict__ outp) {
  __shared__ bf16 t[32][33];
  int bz = blockIdx.z, bx = blockIdx.x;
  int r0 = blockIdx.y * 32;
  const bf16* in; int C, c0, rowoff;
  if (bx < 16) { in = ckv + (long long)bz * 524288; C = 512; c0 = bx * 32;        rowoff = 0; }
  else         { in = kr  + (long long)bz * 65536;  C = 64;  c0 = (bx - 16) * 32; rowoff = 512; }
  int tx = threadIdx.x & 31, ty = threadIdx.x >> 5;   // 32 x 8
  #pragma unroll
  for (int i = 0; i < 32; i += 8)
    t[ty + i][tx] = in[(long long)(r0 + ty + i) * C + (c0 + tx)];
  __syncthreads();
  bf16* outb = outp + (long long)bz * 589824 + (long long)rowoff * 1024;
  #pragma unroll
  for (int i = 0; i < 32; i += 8)
    outb[(long long)(c0 + ty + i) * 1024 + (r0 + tx)] = t[tx][ty + i];
}

__device__ __forceinline__ float block_sum256(float v) {
  #pragma unroll
  for (int o = 32; o > 0; o >>= 1) v += __shfl_xor(v, o, 64);
  __shared__ float red[4];
  int lane = threadIdx.x & 63, w = threadIdx.x >> 6;
  if (lane == 0) red[w] = v;
  __syncthreads();
  return red[0] + red[1] + red[2] + red[3];
}

// fused-G1 row (stride 1088 fp32): [0:512) rmsnorm->ckv ; [512:576) rope->kr ;
// [576:1088) rmsnorm->cq.  One launch.
__global__ __launch_bounds__(256) void rms_all(const float* __restrict__ dq,
    const float* __restrict__ kvw, const float* __restrict__ qw,
    const float* __restrict__ ch, const float* __restrict__ sh,
    bf16* __restrict__ ckv, bf16* __restrict__ kr, bf16* __restrict__ cq) {
  int row = blockIdx.x, t = threadIdx.x;
  const float* xr = dq + (long long)row * 1088;
  long long o = (long long)row * 512;
  // part 1: kv-norm + rope-k
  {
    float v0 = xr[t], v1 = xr[t + 256];
    float ss = block_sum256(v0 * v0 + v1 * v1);
    float sc = rsqrtf(ss * (1.0f / 512.0f) + 1.1920929e-07f);
    ckv[o + t]       = __float2bfloat16(v0 * sc * kvw[t]);
    ckv[o + t + 256] = __float2bfloat16(v1 * sc * kvw[t + 256]);
    if (t < 64) {
      int s = row & (SEQ - 1);
      float a = xr[512 + t], r;
      if (t < 32) r = a * ch[s * 32 + t]      - xr[512 + t + 32] * sh[s * 32 + t];
      else        r = a * ch[s * 32 + t - 32] + xr[512 + t - 32] * sh[s * 32 + t - 32];
      kr[(long long)row * 64 + t] = __float2bfloat16(r);
    }
  }
  __syncthreads();
  // part 2: q-norm
  {
    float v0 = xr[576 + t], v1 = xr[576 + t + 256];
    float ss = block_sum256(v0 * v0 + v1 * v1);
    float sc = rsqrtf(ss * (1.0f / 512.0f) + 1.1920929e-07f);
    cq[o + t]       = __float2bfloat16(v0 * sc * qw[t]);
    cq[o + t + 256] = __float2bfloat16(v1 * sc * qw[t + 256]);
  }
}

// rope for q_r: 256 threads handle 4 rows of 64
__global__ __launch_bounds__(256) void rope_qr(const float* __restrict__ in,
    const float* __restrict__ ch, const float* __restrict__ sh, bf16* __restrict__ out) {
  int row = blockIdx.x * 4 + (threadIdx.x >> 6);
  int t = threadIdx.x & 63;
  const float* xr = in + (long long)row * 64;
  int s = row & (SEQ - 1);
  float a = xr[t], r;
  if (t < 32) r = a * ch[s * 32 + t]      - xr[t + 32] * sh[s * 32 + t];
  else        r = a * ch[s * 32 + t - 32] + xr[t - 32] * sh[s * 32 + t - 32];
  out[(long long)row * 64 + t] = __float2bfloat16(r);
}

// =====================================================================
extern "C" void kernel_launch(void* const* d_in, const int* in_sizes, int n_in,
                              void* d_out, int out_size, void* d_ws, size_t ws_size,
                              hipStream_t stream) {
  const float* x    = (const float*)d_in[0];
  const float* ch   = (const float*)d_in[1];
  const float* sh   = (const float*)d_in[2];
  const float* mask = (const float*)d_in[3];
  const float* wdkv = (const float*)d_in[4];
  const float* bdkv = (const float*)d_in[5];
  const float* kvnw = (const float*)d_in[6];
  const float* wdq  = (const float*)d_in[7];
  const float* bdq  = (const float*)d_in[8];
  const float* qnw  = (const float*)d_in[9];
  const float* wuq  = (const float*)d_in[10];
  const float* buq  = (const float*)d_in[11];
  const float* wqr  = (const float*)d_in[12];
  const float* bqr  = (const float*)d_in[13];
  const float* wuk  = (const float*)d_in[14];
  const float* wuv  = (const float*)d_in[15];
  const float* wo   = (const float*)d_in[16];
  const float* bo   = (const float*)d_in[17];
  float* out = (float*)d_out;
  (void)in_sizes; (void)n_in; (void)out_size; (void)ws_size;

  // ---------- workspace layout (total ~112 MB) ----------
  char* ws = (char*)d_ws;
  bf16* regionA = (bf16*)(ws);                       // 33,554,432 B : xb then wo_b
  bf16* outh    = (bf16*)(ws + 33554432);            // 33,554,432 B
  bf16* wdkv_b  = (bf16*)(ws + 67108864);            //  4,718,592 B  (576x4096)
  bf16* wdq_b   = (bf16*)(ws + 71827456);            //  4,194,304 B  (512x4096, adjacent -> cat)
  bf16* wuq_b   = (bf16*)(ws + 76021760);            //  4,194,304 B
  bf16* wqr_b   = (bf16*)(ws + 80216064);            //     65,536 B
  bf16* wuv_b   = (bf16*)(ws + 80281600);            //  4,194,304 B
  bf16* wuk_b   = (bf16*)(ws + 84475904);            //  4,194,304 B
  bf16* mask_b  = (bf16*)(ws + 88670208);            //  2,097,152 B
  char* regionB = ws + 90767360;                     // 20,971,520 B
  float* dq_cat = (float*)(regionB);                 // 17,825,792 B (phase 1: 4096x1088 fp32)
  bf16* Eb      = (bf16*)(regionB);                  // 16,777,216 B (phase 2)
  bf16* FT      = (bf16*)(regionB + 16777216);       //  4,194,304 B (phase 2)

  bf16* xb   = regionA;          // phase 1 of regionA
  bf16* wo_b = regionA;          // phase 2 of regionA (cast after G1c)

  // ---------- d_out used as scratch (64 MB); all dead before G13 ----------
  char* ob = (char*)d_out;
  bf16* qb      = (bf16*)(ob);                 // 33,554,432 B
  char* U       = ob + 33554432;
  bf16* ckv     = (bf16*)(U);                  // 4,194,304
  bf16* kr      = (bf16*)(U + 4194304);        //   524,288
  bf16* ckvT    = (bf16*)(U + 4718592);        // 4,718,592  (b,576,1024): [ckvT | krT]
  bf16* cq      = (bf16*)(U + 9437184);        // 4,194,304
  float* qr_pre = (float*)(U + 13631488);      // 1,048,576 (also hosts bias_cat before G4)
  bf16* qr_b    = (bf16*)(U + 14680064);       //   524,288
  bf16* GmExt   = (bf16*)(U + 15204352);       // 2,359,296  (b,512,576): [Gm | Mt]
  bf16* base_b  = (bf16*)(U + 17563648);       // 4,194,304  (end 21,757,952)

  float* bias_cat = qr_pre;   // 1088 floats; dead before G4 writes qr_pre

  long long Z = 0;

  // ---- fused early casts (8 jobs, 1 launch) ----
  {
    CastJobs J;
    const float* srcs[8] = {x, wdkv, wdq, wqr, mask, wuq, wuv, wuk};
    bf16* dsts[8] = {xb, wdkv_b, wdq_b, wqr_b, mask_b, wuq_b, wuv_b, wuk_b};
    int n4s[8] = {4194304, 589824, 524288, 8192, 262144, 524288, 524288, 524288};
    int accb = 0;
    for (int j = 0; j < 8; ++j) {
      J.s[j] = srcs[j]; J.d[j] = dsts[j]; J.n4[j] = n4s[j];
      J.b0[j] = accb; accb += (n4s[j] + 255) / 256;
    }
    cast_multi<<<dim3(accb), 256, 0, stream>>>(J);
  }
  // concatenated bias for fused G1+G2
  hipMemcpyAsync(bias_cat, bdkv, 576 * 4, hipMemcpyDeviceToDevice, stream);
  hipMemcpyAsync(bias_cat + 576, bdq, 512 * 4, hipMemcpyDeviceToDevice, stream);

  // G1c (fused G1+G2): dq_cat = x @ [wdkv;wdq]^T + [bdkv;bdq]  (4096 x 1088 x 4096), fp32
  gemm_bt<128, 64, 4, 1, 0, 0, 1><<<dim3(17, 32, 1), 256, 0, stream>>>(
      xb, wdkv_b, dq_cat, bias_cat, nullptr, 4096, 4096, 4096, 1088, 0, 1, Z,Z,Z,Z,Z,Z,Z,Z);
  // fused norms + rope-k (1 launch)
  rms_all<<<dim3(BT), 256, 0, stream>>>(dq_cat, kvnw, qnw, ch, sh, ckv, kr, cq);
  // fused transposes into ckvT_ext (1 launch)
  tr_ckv<<<dim3(18, 32, 4), 256, 0, stream>>>(ckv, kr, ckvT);

  // ---- late cast (xb dead after G1c: regionA free for wo_b) ----
  cast4<<<dim3(16384), 256, 0, stream>>>(wo, wo_b, 4194304);

  // G3: q = cq @ wuq^T + b  (4096 x 4096 x 512), bf16 -> qb   [8-phase 256²]
  gemm256<1, 1><<<dim3(256), 512, 0, stream>>>(
      cq, wuq_b, qb, buq, 512, 512, 512, 4096, 16);

  // G4: qr_pre = cq @ wqr^T + b  (4096 x 64 x 512), fp32   [64x64: 64 blocks]
  gemm_bt<64, 64, 2, 2, 0, 0, 1><<<dim3(1, 64, 1), 256, 0, stream>>>(
      cq, wqr_b, qr_pre, bqr, nullptr, 512, 512, 512, 64, 0, 1, Z,Z,Z,Z,Z,Z,Z,Z);
  rope_qr<<<dim3(BT / 4), 256, 0, stream>>>(qr_pre, ch, sh, qr_b);

  // G6+G7 fused: GmExt[b] (512x576) = ckvT_ext[b][:512] @ ckvT_ext[b]^T
  //   cols 0-511 = G (symmetric), cols 512-575 = Mt
  gemm_bt<128, 64, 4, 1, 1, 0, 0><<<dim3(9, 4, 4), 256, 0, stream>>>(
      ckvT, ckvT, GmExt, nullptr, nullptr, 1024, 1024, 1024, 576, 0, 1,
      589824LL, Z, 589824LL, Z, 294912LL, Z, Z, Z);

  // G8: base[b] = mask @ ckvT[b]^T  (1024 x 512 x 1024), z = b   [BN=64: 256 blocks]
  gemm_bt<128, 64, 4, 1, 1, 0, 0><<<dim3(8, 8, 4), 256, 0, stream>>>(
      mask_b, ckvT, base_b, nullptr, nullptr, 1024, 1024, 1024, 512, 0, 1,
      Z, Z, 589824LL, Z, 524288LL, Z, Z, Z);

  // G9: base[b] += qr[b] @ Mt[b]^T   (1024 x 512 x 64); Mt = GmExt[:,512:], ldb=576
  gemm_bt<128, 64, 4, 1, 1, 2, 0><<<dim3(8, 8, 4), 256, 0, stream>>>(
      qr_b, GmExt + 512, base_b, nullptr, base_b, 64, 64, 576, 512, 512, 1,
      65536LL, Z, 294912LL, Z, 524288LL, Z, 524288LL, Z);

  // G10: outh = base @ wuv^T  (4096 x 4096 x 512), bf16   [8-phase 256²]
  gemm256<1, 0><<<dim3(256), 512, 0, stream>>>(
      base_b, wuv_b, outh, nullptr, 512, 512, 512, 4096, 16);

  // E[b,h] = wuv_h @ G[b]^T  (128 x 512 x 512), z = (b,h); G = GmExt[:, :512], ldb=576
  gemm_bt<128, 128, 2, 2, 1, 0, 0><<<dim3(4, 1, 128), 256, 0, stream>>>(
      wuv_b, GmExt, Eb, nullptr, nullptr, 512, 512, 576, 512, 0, 32,
      Z, 65536LL, 294912LL, Z, 2097152LL, 65536LL, Z, Z);

  // FT[b,h] = E[b,h] @ wuk_h^T  (128 x 128 x 512), z = (b,h)   [BN=64: 256 blocks]
  gemm_bt<128, 64, 4, 1, 1, 0, 0><<<dim3(2, 1, 128), 256, 0, stream>>>(
      Eb, wuk_b, FT, nullptr, nullptr, 512, 512, 512, 128, 0, 32,
      2097152LL, 65536LL, Z, 65536LL, 524288LL, 16384LL, Z, Z);

  // G12: outh[b,:,h*128:+128] += qb[b,:,h*128:+128] @ FT[b,h]^T  (1024 x 128 x 128)
  gemm_bt<128, 128, 2, 2, 1, 2, 0><<<dim3(1, 8, 128), 256, 0, stream>>>(
      qb, FT, outh, nullptr, outh, 128, 4096, 128, 4096, 4096, 32,
      4194304LL, 128LL, 524288LL, 16384LL, 4194304LL, 128LL, 4194304LL, 128LL);

  // G13: out = outh @ wo^T + bo  (4096 x 4096 x 4096), fp32   [8-phase 256²]
  gemm256<0, 1><<<dim3(256), 512, 0, stream>>>(
      outh, wo_b, out, bo, 4096, 4096, 4096, 4096, 16);
}